// Round 14
// baseline (117.821 us; speedup 1.0000x reference)
//
#include <hip/hip_runtime.h>

#define DIM    512
#define NCLS   128
#define NCENT  8
#define TM     64
#define WSLOT  64      // padded neighbor-slot width (max degree guard)
#define NB     64      // fixed grid for hist / scan+scatter
#define KC2    64      // K-chunk staged in LDS for MFMA gemm
#define KP2    72      // padded LDS row stride in bf16 (144B: 2-way bank alias = free)

typedef unsigned short ushort_t;
typedef unsigned int   uint_t;
typedef __attribute__((ext_vector_type(8))) short bf16x8;   // 8 bf16 (4 VGPRs)
typedef __attribute__((ext_vector_type(4))) float f32x4;    // MFMA C/D

static __device__ __forceinline__ ushort_t f2bf(float f) {
    uint_t x = __float_as_uint(f);
    uint_t r = (x + 0x7fffu + ((x >> 16) & 1u)) >> 16;   // RTNE (finite inputs)
    return (ushort_t)r;
}
static __device__ __forceinline__ float bf_lo(uint_t w) {
    return __uint_as_float(w << 16);
}
static __device__ __forceinline__ float bf_hi(uint_t w) {
    return __uint_as_float(w & 0xffff0000u);
}

// --- fused prep: [0,nprep) h->hb + q; [nprep,+nwt) Wt->wtb; [+nsc) edge scatter

__global__ __launch_bounds__(256) void fused_prep_kernel(
        const float* __restrict__ h, const float* __restrict__ Ws,
        const float* __restrict__ Wt, const int* __restrict__ esrc,
        const int* __restrict__ edst, ushort_t* __restrict__ hb,
        float* __restrict__ q, ushort_t* __restrict__ wtb,
        int* __restrict__ cnt, int* __restrict__ slots,
        int N, int E, int nprep, int nwt, int total8) {
    int b = blockIdx.x;
    if (b >= nprep + nwt) {                             // edge scatter (atomics)
        int i = (b - nprep - nwt) * 256 + threadIdx.x;
        if (i < E) {
            int d = edst[i];
            int k = atomicAdd(&cnt[d], 1);
            if (k < WSLOT) slots[(size_t)d * WSLOT + k] = esrc[i];
        }
        return;
    }
    if (b >= nprep) {                                   // Wt -> bf16 transcode
        int i = (b - nprep) * 256 + threadIdx.x;
        if (i < total8) {
            const float* src = Wt + (size_t)i * 8;
            float4 a = *(const float4*)src;
            float4 bb = *(const float4*)(src + 4);
            union { ushort_t us[8]; uint4 v; } pk;
            pk.us[0] = f2bf(a.x);  pk.us[1] = f2bf(a.y);
            pk.us[2] = f2bf(a.z);  pk.us[3] = f2bf(a.w);
            pk.us[4] = f2bf(bb.x); pk.us[5] = f2bf(bb.y);
            pk.us[6] = f2bf(bb.z); pk.us[7] = f2bf(bb.w);
            *(uint4*)(wtb + (size_t)i * 8) = pk.v;
        }
        return;
    }
    int wid = (b * 256 + threadIdx.x) >> 6;             // node
    int lane = threadIdx.x & 63;
    if (wid >= N) return;                               // wave-uniform exit

    const float* row = h + (size_t)wid * DIM + lane * 8;
    float4 a = *(const float4*)row;
    float4 bb = *(const float4*)(row + 4);
    float fa[8] = {a.x, a.y, a.z, a.w, bb.x, bb.y, bb.z, bb.w};

    union { ushort_t us[8]; uint4 v; } pk;
    #pragma unroll
    for (int i = 0; i < 8; ++i) pk.us[i] = f2bf(fa[i]);
    *(uint4*)(hb + (size_t)wid * DIM + lane * 8) = pk.v;

    float qv = 0.f;
    #pragma unroll
    for (int c = 0; c < NCENT; ++c) {
        const float* w = Ws + c * DIM + lane * 8;
        float4 w0 = *(const float4*)w;
        float4 w1 = *(const float4*)(w + 4);
        float p = fa[0]*w0.x + fa[1]*w0.y + fa[2]*w0.z + fa[3]*w0.w
                + fa[4]*w1.x + fa[5]*w1.y + fa[6]*w1.z + fa[7]*w1.w;
        #pragma unroll
        for (int s = 32; s > 0; s >>= 1) p += __shfl_xor(p, s, 64);
        if (lane == c) qv = p;
    }
    if (lane < NCENT) q[(size_t)wid * NCENT + lane] = qv;
}

// --- gather-mean (bf16, 17 rows in flight) + fused f32 q-router --------------
// Summation order identical to r12/r13 (k ascending); no global atomics.

__global__ __launch_bounds__(256) void gather_route_kernel(
        const ushort_t* __restrict__ hb, const int* __restrict__ cnt,
        const int* __restrict__ slots, const float* __restrict__ q,
        ushort_t* __restrict__ hmb, int* __restrict__ route, int N) {
    int wid = (blockIdx.x * 256 + threadIdx.x) >> 6;   // node
    int lane = threadIdx.x & 63;
    if (wid >= N) return;

    int cn = cnt[wid]; if (cn > WSLOT) cn = WSLOT;
    int myslot = (lane < cn) ? slots[(size_t)wid * WSLOT + lane] : 0;

    // early q-row load for my slot (overlaps the gather)
    float qs[NCENT];
    if (lane < cn) {
        const float* qr = q + (size_t)myslot * NCENT;
        float4 q0 = *(const float4*)qr;
        float4 q1 = *(const float4*)(qr + 4);
        qs[0]=q0.x; qs[1]=q0.y; qs[2]=q0.z; qs[3]=q0.w;
        qs[4]=q1.x; qs[5]=q1.y; qs[6]=q1.z; qs[7]=q1.w;
    } else {
        #pragma unroll
        for (int c = 0; c < NCENT; ++c) qs[c] = 0.f;
    }

    // self row + up to 16 slot rows issued before any use (17 in flight)
    uint4 su = *(const uint4*)(hb + (size_t)wid * DIM + lane * 8);
    uint4 u[16];
    int m = cn < 16 ? cn : 16;                          // wave-uniform
    #pragma unroll
    for (int k = 0; k < 16; ++k) {
        int s = __shfl(myslot, k, 64);
        if (k < m) u[k] = *(const uint4*)(hb + (size_t)s * DIM + lane * 8);
    }

    float acc[8];
    acc[0] = bf_lo(su.x); acc[1] = bf_hi(su.x);
    acc[2] = bf_lo(su.y); acc[3] = bf_hi(su.y);
    acc[4] = bf_lo(su.z); acc[5] = bf_hi(su.z);
    acc[6] = bf_lo(su.w); acc[7] = bf_hi(su.w);
    #pragma unroll
    for (int k = 0; k < 16; ++k) {
        if (k < m) {
            acc[0] += bf_lo(u[k].x); acc[1] += bf_hi(u[k].x);
            acc[2] += bf_lo(u[k].y); acc[3] += bf_hi(u[k].y);
            acc[4] += bf_lo(u[k].z); acc[5] += bf_hi(u[k].z);
            acc[6] += bf_lo(u[k].w); acc[7] += bf_hi(u[k].w);
        }
    }
    int j = 16;
    for (; j + 8 <= cn; j += 8) {
        uint4 v[8];
        #pragma unroll
        for (int k = 0; k < 8; ++k) {
            int s = __shfl(myslot, j + k, 64);
            v[k] = *(const uint4*)(hb + (size_t)s * DIM + lane * 8);
        }
        #pragma unroll
        for (int k = 0; k < 8; ++k) {
            acc[0] += bf_lo(v[k].x); acc[1] += bf_hi(v[k].x);
            acc[2] += bf_lo(v[k].y); acc[3] += bf_hi(v[k].y);
            acc[4] += bf_lo(v[k].z); acc[5] += bf_hi(v[k].z);
            acc[6] += bf_lo(v[k].w); acc[7] += bf_hi(v[k].w);
        }
    }
    for (; j < cn; ++j) {
        int s = __shfl(myslot, j, 64);
        uint4 v = *(const uint4*)(hb + (size_t)s * DIM + lane * 8);
        acc[0] += bf_lo(v.x); acc[1] += bf_hi(v.x);
        acc[2] += bf_lo(v.y); acc[3] += bf_hi(v.y);
        acc[4] += bf_lo(v.z); acc[5] += bf_hi(v.z);
        acc[6] += bf_lo(v.w); acc[7] += bf_hi(v.w);
    }
    float inv = 1.0f / (float)(cn + 1);
    union { ushort_t us[8]; uint4 v; } pk;
    #pragma unroll
    for (int k = 0; k < 8; ++k) pk.us[k] = f2bf(acc[k] * inv);
    *(uint4*)(hmb + (size_t)wid * DIM + lane * 8) = pk.v;

    // router reduce: tot[c] = sum over lanes of qs[c] (f32, exact slots sum)
    #pragma unroll
    for (int c = 0; c < NCENT; ++c) {
        float v = qs[c];
        #pragma unroll
        for (int s = 32; s > 0; s >>= 1) v += __shfl_xor(v, s, 64);
        qs[c] = v;
    }
    if (lane == 0) {
        const float* qn = q + (size_t)wid * NCENT;     // self-loop q row
        int best = 0; float bv = qs[0] + qn[0];
        #pragma unroll
        for (int c = 1; c < NCENT; ++c) {
            float v = qs[c] + qn[c];
            if (v > bv) { bv = v; best = c; }          // strict > = first max
        }
        route[wid] = best;
    }
}

// --- counting sort, phase 1: per-block 8-bin histogram (LDS only) ------------

__global__ __launch_bounds__(256) void route_hist_kernel(const int* __restrict__ route,
                                                         int* __restrict__ bhist, int N) {
    __shared__ int lh[NCENT];
    int t = threadIdx.x;
    if (t < NCENT) lh[t] = 0;
    __syncthreads();
    for (int i = blockIdx.x * 256 + t; i < N; i += NB * 256)
        atomicAdd(&lh[route[i]], 1);
    __syncthreads();
    if (t < NCENT) bhist[blockIdx.x * NCENT + t] = lh[t];
}

// --- counting sort, fused phase 2+3: redundant scan + LDS-cursor scatter -----

__global__ __launch_bounds__(256) void scan_scatter_kernel(
        const int* __restrict__ bhist, const int* __restrict__ route,
        int* __restrict__ nlist, int* __restrict__ goff,
        int* __restrict__ tloff, int N) {
    __shared__ int bh[NB * NCENT];
    __shared__ int pre[NB][NCENT];
    __shared__ int go[NCENT + 1], tl[NCENT + 1];
    __shared__ int lcur[NCENT];
    int t = threadIdx.x;

    for (int i = t; i < NB * NCENT; i += 256) bh[i] = bhist[i];
    __syncthreads();
    if (t < NCENT) {                    // thread t = center: serial scan (LDS)
        int run = 0;
        for (int b = 0; b < NB; ++b) {
            pre[b][t] = run;
            run += bh[b * NCENT + t];
        }
        go[t] = run;                    // totals (temporarily)
    }
    __syncthreads();
    if (t == 0) {
        int g = 0, tt = 0;
        for (int c = 0; c < NCENT; ++c) {
            int gc = go[c];
            go[c] = g; tl[c] = tt;
            g += gc; tt += (gc + TM - 1) / TM;
        }
        go[NCENT] = g; tl[NCENT] = tt;
    }
    __syncthreads();
    if (t < NCENT) lcur[t] = go[t] + pre[blockIdx.x][t];
    __syncthreads();
    for (int i = blockIdx.x * 256 + t; i < N; i += NB * 256) {
        int p = atomicAdd(&lcur[route[i]], 1);       // LDS atomic — no hot L2 line
        nlist[p] = i;
    }
    if (blockIdx.x == 0 && t < NCENT + 1) { goff[t] = go[t]; tloff[t] = tl[t]; }
}

// --- grouped GEMM via bf16 MFMA: out[n,:] = hmb[n,:] @ wtb[route]^T ----------
// C/D frag: col = l&15, row = (l>>4)*4 + reg (m89/m91-verified layout).

__global__ __launch_bounds__(256) void gemm_mfma_kernel(
        const ushort_t* __restrict__ hmb, const int* __restrict__ nlist,
        const int* __restrict__ goff, const int* __restrict__ tloff,
        const ushort_t* __restrict__ wtb, float* __restrict__ out) {
    __shared__ ushort_t a_s[TM * KP2];      // 9216 B
    __shared__ ushort_t b_s[NCLS * KP2];    // 18432 B
    __shared__ int nl_s[TM];

    int b = blockIdx.x;
    if (b >= tloff[NCENT]) return;
    int c = 0;
    while (b >= tloff[c + 1]) ++c;
    int row0 = goff[c] + (b - tloff[c]) * TM;
    int mrows = goff[c + 1] - row0; if (mrows > TM) mrows = TM;

    int tid = threadIdx.x;
    int wv = tid >> 6;                      // wave: rows [wv*16, wv*16+16)
    int lane = tid & 63;

    if (tid < TM) nl_s[tid] = nlist[row0 + (tid < mrows ? tid : mrows - 1)];
    __syncthreads();

    f32x4 acc[8];
    #pragma unroll
    for (int t = 0; t < 8; ++t) acc[t] = (f32x4){0.f, 0.f, 0.f, 0.f};

    const ushort_t* wt_c = wtb + (size_t)c * NCLS * DIM;

    for (int k0 = 0; k0 < DIM; k0 += KC2) {
        #pragma unroll
        for (int r = 0; r < 2; ++r) {               // stage A: 64x64 bf16
            int idx = tid + 256 * r;                // 0..511
            int row = idx >> 3;
            int kq = (idx & 7) * 8;
            int nd = nl_s[row];
            uint4 v = *(const uint4*)(hmb + (size_t)nd * DIM + k0 + kq);
            *(uint4*)&a_s[row * KP2 + kq] = v;
        }
        #pragma unroll
        for (int r = 0; r < 4; ++r) {               // stage B: 128x64 bf16
            int idx = tid + 256 * r;                // 0..1023
            int row = idx >> 3;
            int kq = (idx & 7) * 8;
            uint4 v = *(const uint4*)(wt_c + (size_t)row * DIM + k0 + kq);
            *(uint4*)&b_s[row * KP2 + kq] = v;
        }
        __syncthreads();
        #pragma unroll
        for (int s = 0; s < 2; ++s) {               // two K=32 steps
            int kof = s * 32 + (lane >> 4) * 8;
            bf16x8 af = *(const bf16x8*)&a_s[(wv * 16 + (lane & 15)) * KP2 + kof];
            #pragma unroll
            for (int t = 0; t < 8; ++t) {
                bf16x8 bf = *(const bf16x8*)&b_s[(t * 16 + (lane & 15)) * KP2 + kof];
                acc[t] = __builtin_amdgcn_mfma_f32_16x16x32_bf16(af, bf, acc[t], 0, 0, 0);
            }
        }
        __syncthreads();
    }

    #pragma unroll
    for (int r4 = 0; r4 < 4; ++r4) {
        int row = wv * 16 + (lane >> 4) * 4 + r4;
        if (row < mrows) {
            int nd = nl_s[row];
            float* orow = out + (size_t)nd * NCLS + (lane & 15);
            #pragma unroll
            for (int t = 0; t < 8; ++t)
                orow[t * 16] = acc[t][r4];
        }
    }
}

// --- Fallback: fused slots-based per-node kernel (f32 end-to-end) ------------

__global__ __launch_bounds__(256) void node_kernel(const float* __restrict__ h,
                                                   const int* __restrict__ cnt,
                                                   const int* __restrict__ slots,
                                                   const float* __restrict__ Ws,
                                                   const float* __restrict__ Wt,
                                                   float* __restrict__ out) {
    int node = blockIdx.x;
    int t = threadIdx.x;
    __shared__ float hm[DIM];
    __shared__ float sc[NCENT];
    __shared__ int route_s;

    int d0 = t * 2;
    float2 acc = *(const float2*)(h + (size_t)node * DIM + d0);
    int cn = cnt[node]; if (cn > WSLOT) cn = WSLOT;
    const int* sl = slots + (size_t)node * WSLOT;
    for (int j = 0; j < cn; ++j) {
        float2 v = *(const float2*)(h + (size_t)sl[j] * DIM + d0);
        acc.x += v.x; acc.y += v.y;
    }
    float inv = 1.0f / (float)(cn + 1);
    hm[d0] = acc.x * inv; hm[d0 + 1] = acc.y * inv;
    __syncthreads();
    if (t < NCENT) {
        const float* w = Ws + t * DIM;
        float s = 0.f;
        for (int d = 0; d < DIM; d += 4) {
            float4 a = *(const float4*)(&hm[d]);
            float4 b = *(const float4*)(w + d);
            s += a.x * b.x + a.y * b.y + a.z * b.z + a.w * b.w;
        }
        sc[t] = s;
    }
    __syncthreads();
    if (t == 0) {
        int best = 0; float bv = sc[0];
        #pragma unroll
        for (int c = 1; c < NCENT; ++c)
            if (sc[c] > bv) { bv = sc[c]; best = c; }
        route_s = best;
    }
    __syncthreads();
    int route = route_s;
    if (t < NCLS) {
        const float* w = Wt + ((size_t)route * NCLS + t) * DIM;
        float s = 0.f;
        for (int d = 0; d < DIM; d += 4) {
            float4 a = *(const float4*)(&hm[d]);
            float4 b = *(const float4*)(w + d);
            s += a.x * b.x + a.y * b.y + a.z * b.z + a.w * b.w;
        }
        out[(size_t)node * NCLS + t] = s;
    }
}

// --- launch ------------------------------------------------------------------

extern "C" void kernel_launch(void* const* d_in, const int* in_sizes, int n_in,
                              void* d_out, int out_size, void* d_ws, size_t ws_size,
                              hipStream_t stream) {
    const float* h   = (const float*)d_in[0];
    const int*   ei  = (const int*)d_in[1];
    const float* Ws  = (const float*)d_in[2];
    const float* Wt  = (const float*)d_in[3];
    float*       out = (float*)d_out;

    int N = in_sizes[0] / DIM;
    int E = in_sizes[1] / 2;
    int wt_elems = in_sizes[3];              // 8*128*512
    const int* esrc = ei;
    const int* edst = ei + E;

    int* wsp    = (int*)d_ws;
    int* cnt    = wsp;                       // N
    int* route  = cnt + N;                   // N
    int* goff   = route + N;                 // 9
    int* tloff  = goff + NCENT + 1;          // 9
    int* bhist  = tloff + NCENT + 1;         // NB*8
    int* nlist  = bhist + NB * NCENT;        // N
    int* slots  = nlist + N;                 // N*WSLOT
    size_t iw   = (size_t)(3 * N) + 2 * (NCENT + 1) + NB * NCENT
                + (size_t)N * WSLOT;
    size_t q_off  = ((iw * 4 + 255) & ~(size_t)255);
    float* q    = (float*)((char*)d_ws + q_off);               // N*8 f32
    size_t hb_off = ((q_off + (size_t)N * NCENT * 4 + 255) & ~(size_t)255);
    ushort_t* hb = (ushort_t*)((char*)d_ws + hb_off);          // N*512 bf16
    size_t hmb_off = ((hb_off + (size_t)N * DIM * 2 + 255) & ~(size_t)255);
    ushort_t* hmb = (ushort_t*)((char*)d_ws + hmb_off);        // N*512 bf16
    size_t wtb_off = ((hmb_off + (size_t)N * DIM * 2 + 255) & ~(size_t)255);
    ushort_t* wtb = (ushort_t*)((char*)d_ws + wtb_off);        // 8*128*512 bf16
    size_t need = wtb_off + (size_t)wt_elems * 2;

    hipMemsetAsync(cnt, 0, (size_t)N * sizeof(int), stream);

    if (ws_size >= need) {
        int nprep = (N + 3) / 4;
        int total8 = wt_elems / 8;
        int nwt = (total8 + 255) / 256;
        int nsc = (E + 255) / 256;
        fused_prep_kernel<<<nprep + nwt + nsc, 256, 0, stream>>>(
            h, Ws, Wt, esrc, edst, hb, q, wtb, cnt, slots,
            N, E, nprep, nwt, total8);
        gather_route_kernel<<<(N + 3) / 4, 256, 0, stream>>>(hb, cnt, slots, q,
                                                             hmb, route, N);
        route_hist_kernel<<<NB, 256, 0, stream>>>(route, bhist, N);
        scan_scatter_kernel<<<NB, 256, 0, stream>>>(bhist, route, nlist,
                                                    goff, tloff, N);
        int maxtiles = N / TM + NCENT + 1;
        gemm_mfma_kernel<<<maxtiles, 256, 0, stream>>>(hmb, nlist, goff, tloff, wtb, out);
    } else {
        // fallback: edge scatter + fused per-node kernel (f32)
        fused_prep_kernel<<<0 + 0 + (E + 255) / 256, 256, 0, stream>>>(
            h, Ws, Wt, esrc, edst, (ushort_t*)nullptr, (float*)nullptr,
            (ushort_t*)nullptr, cnt, slots, N, E, 0, 0, 0);
        node_kernel<<<N, 256, 0, stream>>>(h, cnt, slots, Ws, Wt, out);
    }
}

// Round 15
// 112.283 us; speedup vs baseline: 1.0493x; 1.0493x over previous
//
#include <hip/hip_runtime.h>

#define DIM    512
#define NCLS   128
#define NCENT  8
#define TM     64
#define WSLOT  64      // padded neighbor-slot width (max degree guard)
#define NB     64      // fixed grid for hist / scan+scatter
#define KC2    64      // K-chunk staged in LDS for MFMA gemm
#define KP2    72      // padded LDS row stride in bf16 (144B: 2-way bank alias = free)

typedef unsigned short ushort_t;
typedef unsigned int   uint_t;
typedef __attribute__((ext_vector_type(8))) short bf16x8;   // 8 bf16 (4 VGPRs)
typedef __attribute__((ext_vector_type(4))) float f32x4;    // MFMA C/D

static __device__ __forceinline__ ushort_t f2bf(float f) {
    uint_t x = __float_as_uint(f);
    uint_t r = (x + 0x7fffu + ((x >> 16) & 1u)) >> 16;   // RTNE (finite inputs)
    return (ushort_t)r;
}
static __device__ __forceinline__ float bf_lo(uint_t w) {
    return __uint_as_float(w << 16);
}
static __device__ __forceinline__ float bf_hi(uint_t w) {
    return __uint_as_float(w & 0xffff0000u);
}

// --- prep (+Wt transcode tail blocks): hb = bf16(h); q = h @ Ws^T (f32). -----

__global__ __launch_bounds__(256) void prep_kernel(const float* __restrict__ h,
                                                   const float* __restrict__ Ws,
                                                   const float* __restrict__ Wt,
                                                   ushort_t* __restrict__ hb,
                                                   float* __restrict__ q,
                                                   ushort_t* __restrict__ wtb,
                                                   int N, int nprep, int total8) {
    if ((int)blockIdx.x >= nprep) {                     // Wt -> bf16 transcode
        int i = (blockIdx.x - nprep) * 256 + threadIdx.x;
        if (i < total8) {
            const float* src = Wt + (size_t)i * 8;
            float4 a = *(const float4*)src;
            float4 b = *(const float4*)(src + 4);
            union { ushort_t us[8]; uint4 v; } pk;
            pk.us[0] = f2bf(a.x); pk.us[1] = f2bf(a.y);
            pk.us[2] = f2bf(a.z); pk.us[3] = f2bf(a.w);
            pk.us[4] = f2bf(b.x); pk.us[5] = f2bf(b.y);
            pk.us[6] = f2bf(b.z); pk.us[7] = f2bf(b.w);
            *(uint4*)(wtb + (size_t)i * 8) = pk.v;
        }
        return;
    }
    int wid = (blockIdx.x * 256 + threadIdx.x) >> 6;   // node
    int lane = threadIdx.x & 63;
    if (wid >= N) return;                               // wave-uniform exit

    const float* row = h + (size_t)wid * DIM + lane * 8;
    float4 a = *(const float4*)row;
    float4 b = *(const float4*)(row + 4);
    float fa[8] = {a.x, a.y, a.z, a.w, b.x, b.y, b.z, b.w};

    union { ushort_t us[8]; uint4 v; } pk;
    #pragma unroll
    for (int i = 0; i < 8; ++i) pk.us[i] = f2bf(fa[i]);
    *(uint4*)(hb + (size_t)wid * DIM + lane * 8) = pk.v;

    float qv = 0.f;
    #pragma unroll
    for (int c = 0; c < NCENT; ++c) {
        const float* w = Ws + c * DIM + lane * 8;
        float4 w0 = *(const float4*)w;
        float4 w1 = *(const float4*)(w + 4);
        float p = fa[0]*w0.x + fa[1]*w0.y + fa[2]*w0.z + fa[3]*w0.w
                + fa[4]*w1.x + fa[5]*w1.y + fa[6]*w1.z + fa[7]*w1.w;
        #pragma unroll
        for (int s = 32; s > 0; s >>= 1) p += __shfl_xor(p, s, 64);
        if (lane == c) qv = p;
    }
    if (lane < NCENT) q[(size_t)wid * NCENT + lane] = qv;
}

// --- padded-slot CSR: one atomic pass (cnt spread over 80KB — no hot line) ---

__global__ __launch_bounds__(256) void scatter_pad_kernel(const int* __restrict__ src,
                                                          const int* __restrict__ dst,
                                                          int* __restrict__ cnt,
                                                          int* __restrict__ slots, int E) {
    int i = blockIdx.x * 256 + threadIdx.x;
    if (i < E) {
        int d = dst[i];
        int k = atomicAdd(&cnt[d], 1);
        if (k < WSLOT) slots[(size_t)d * WSLOT + k] = src[i];
    }
}

// --- gather-mean (bf16, 17 rows in flight) + fused f32 q-router --------------
// Summation order identical to r12/r13 (k ascending); no global atomics.

__global__ __launch_bounds__(256) void gather_route_kernel(
        const ushort_t* __restrict__ hb, const int* __restrict__ cnt,
        const int* __restrict__ slots, const float* __restrict__ q,
        ushort_t* __restrict__ hmb, int* __restrict__ route, int N) {
    int wid = (blockIdx.x * 256 + threadIdx.x) >> 6;   // node
    int lane = threadIdx.x & 63;
    if (wid >= N) return;

    int cn = cnt[wid]; if (cn > WSLOT) cn = WSLOT;
    int myslot = (lane < cn) ? slots[(size_t)wid * WSLOT + lane] : 0;

    // early q-row load for my slot (overlaps the gather)
    float qs[NCENT];
    if (lane < cn) {
        const float* qr = q + (size_t)myslot * NCENT;
        float4 q0 = *(const float4*)qr;
        float4 q1 = *(const float4*)(qr + 4);
        qs[0]=q0.x; qs[1]=q0.y; qs[2]=q0.z; qs[3]=q0.w;
        qs[4]=q1.x; qs[5]=q1.y; qs[6]=q1.z; qs[7]=q1.w;
    } else {
        #pragma unroll
        for (int c = 0; c < NCENT; ++c) qs[c] = 0.f;
    }

    // self row + up to 16 slot rows issued before any use (17 in flight)
    uint4 su = *(const uint4*)(hb + (size_t)wid * DIM + lane * 8);
    uint4 u[16];
    int m = cn < 16 ? cn : 16;                          // wave-uniform
    #pragma unroll
    for (int k = 0; k < 16; ++k) {
        int s = __shfl(myslot, k, 64);
        if (k < m) u[k] = *(const uint4*)(hb + (size_t)s * DIM + lane * 8);
    }

    float acc[8];
    acc[0] = bf_lo(su.x); acc[1] = bf_hi(su.x);
    acc[2] = bf_lo(su.y); acc[3] = bf_hi(su.y);
    acc[4] = bf_lo(su.z); acc[5] = bf_hi(su.z);
    acc[6] = bf_lo(su.w); acc[7] = bf_hi(su.w);
    #pragma unroll
    for (int k = 0; k < 16; ++k) {
        if (k < m) {
            acc[0] += bf_lo(u[k].x); acc[1] += bf_hi(u[k].x);
            acc[2] += bf_lo(u[k].y); acc[3] += bf_hi(u[k].y);
            acc[4] += bf_lo(u[k].z); acc[5] += bf_hi(u[k].z);
            acc[6] += bf_lo(u[k].w); acc[7] += bf_hi(u[k].w);
        }
    }
    int j = 16;
    for (; j + 8 <= cn; j += 8) {
        uint4 v[8];
        #pragma unroll
        for (int k = 0; k < 8; ++k) {
            int s = __shfl(myslot, j + k, 64);
            v[k] = *(const uint4*)(hb + (size_t)s * DIM + lane * 8);
        }
        #pragma unroll
        for (int k = 0; k < 8; ++k) {
            acc[0] += bf_lo(v[k].x); acc[1] += bf_hi(v[k].x);
            acc[2] += bf_lo(v[k].y); acc[3] += bf_hi(v[k].y);
            acc[4] += bf_lo(v[k].z); acc[5] += bf_hi(v[k].z);
            acc[6] += bf_lo(v[k].w); acc[7] += bf_hi(v[k].w);
        }
    }
    for (; j < cn; ++j) {
        int s = __shfl(myslot, j, 64);
        uint4 v = *(const uint4*)(hb + (size_t)s * DIM + lane * 8);
        acc[0] += bf_lo(v.x); acc[1] += bf_hi(v.x);
        acc[2] += bf_lo(v.y); acc[3] += bf_hi(v.y);
        acc[4] += bf_lo(v.z); acc[5] += bf_hi(v.z);
        acc[6] += bf_lo(v.w); acc[7] += bf_hi(v.w);
    }
    float inv = 1.0f / (float)(cn + 1);
    union { ushort_t us[8]; uint4 v; } pk;
    #pragma unroll
    for (int k = 0; k < 8; ++k) pk.us[k] = f2bf(acc[k] * inv);
    *(uint4*)(hmb + (size_t)wid * DIM + lane * 8) = pk.v;

    // router reduce: tot[c] = sum over lanes of qs[c] (f32, exact slots sum)
    #pragma unroll
    for (int c = 0; c < NCENT; ++c) {
        float v = qs[c];
        #pragma unroll
        for (int s = 32; s > 0; s >>= 1) v += __shfl_xor(v, s, 64);
        qs[c] = v;
    }
    if (lane == 0) {
        const float* qn = q + (size_t)wid * NCENT;     // self-loop q row
        int best = 0; float bv = qs[0] + qn[0];
        #pragma unroll
        for (int c = 1; c < NCENT; ++c) {
            float v = qs[c] + qn[c];
            if (v > bv) { bv = v; best = c; }          // strict > = first max
        }
        route[wid] = best;
    }
}

// --- counting sort, phase 1: per-block 8-bin histogram (LDS only) ------------

__global__ __launch_bounds__(256) void route_hist_kernel(const int* __restrict__ route,
                                                         int* __restrict__ bhist, int N) {
    __shared__ int lh[NCENT];
    int t = threadIdx.x;
    if (t < NCENT) lh[t] = 0;
    __syncthreads();
    for (int i = blockIdx.x * 256 + t; i < N; i += NB * 256)
        atomicAdd(&lh[route[i]], 1);
    __syncthreads();
    if (t < NCENT) bhist[blockIdx.x * NCENT + t] = lh[t];
}

// --- counting sort, fused phase 2+3: redundant scan + LDS-cursor scatter -----

__global__ __launch_bounds__(256) void scan_scatter_kernel(
        const int* __restrict__ bhist, const int* __restrict__ route,
        int* __restrict__ nlist, int* __restrict__ goff,
        int* __restrict__ tloff, int N) {
    __shared__ int bh[NB * NCENT];
    __shared__ int pre[NB][NCENT];
    __shared__ int go[NCENT + 1], tl[NCENT + 1];
    __shared__ int lcur[NCENT];
    int t = threadIdx.x;

    for (int i = t; i < NB * NCENT; i += 256) bh[i] = bhist[i];
    __syncthreads();
    if (t < NCENT) {                    // thread t = center: serial scan (LDS)
        int run = 0;
        for (int b = 0; b < NB; ++b) {
            pre[b][t] = run;
            run += bh[b * NCENT + t];
        }
        go[t] = run;                    // totals (temporarily)
    }
    __syncthreads();
    if (t == 0) {
        int g = 0, tt = 0;
        for (int c = 0; c < NCENT; ++c) {
            int gc = go[c];
            go[c] = g; tl[c] = tt;
            g += gc; tt += (gc + TM - 1) / TM;
        }
        go[NCENT] = g; tl[NCENT] = tt;
    }
    __syncthreads();
    if (t < NCENT) lcur[t] = go[t] + pre[blockIdx.x][t];
    __syncthreads();
    for (int i = blockIdx.x * 256 + t; i < N; i += NB * 256) {
        int p = atomicAdd(&lcur[route[i]], 1);       // LDS atomic — no hot L2 line
        nlist[p] = i;
    }
    if (blockIdx.x == 0 && t < NCENT + 1) { goff[t] = go[t]; tloff[t] = tl[t]; }
}

// --- grouped GEMM via bf16 MFMA: out[n,:] = hmb[n,:] @ wtb[route]^T ----------
// C/D frag: col = l&15, row = (l>>4)*4 + reg (m89/m91-verified layout).

__global__ __launch_bounds__(256) void gemm_mfma_kernel(
        const ushort_t* __restrict__ hmb, const int* __restrict__ nlist,
        const int* __restrict__ goff, const int* __restrict__ tloff,
        const ushort_t* __restrict__ wtb, float* __restrict__ out) {
    __shared__ ushort_t a_s[TM * KP2];      // 9216 B
    __shared__ ushort_t b_s[NCLS * KP2];    // 18432 B
    __shared__ int nl_s[TM];

    int b = blockIdx.x;
    if (b >= tloff[NCENT]) return;
    int c = 0;
    while (b >= tloff[c + 1]) ++c;
    int row0 = goff[c] + (b - tloff[c]) * TM;
    int mrows = goff[c + 1] - row0; if (mrows > TM) mrows = TM;

    int tid = threadIdx.x;
    int wv = tid >> 6;                      // wave: rows [wv*16, wv*16+16)
    int lane = tid & 63;

    if (tid < TM) nl_s[tid] = nlist[row0 + (tid < mrows ? tid : mrows - 1)];
    __syncthreads();

    f32x4 acc[8];
    #pragma unroll
    for (int t = 0; t < 8; ++t) acc[t] = (f32x4){0.f, 0.f, 0.f, 0.f};

    const ushort_t* wt_c = wtb + (size_t)c * NCLS * DIM;

    for (int k0 = 0; k0 < DIM; k0 += KC2) {
        #pragma unroll
        for (int r = 0; r < 2; ++r) {               // stage A: 64x64 bf16
            int idx = tid + 256 * r;                // 0..511
            int row = idx >> 3;
            int kq = (idx & 7) * 8;
            int nd = nl_s[row];
            uint4 v = *(const uint4*)(hmb + (size_t)nd * DIM + k0 + kq);
            *(uint4*)&a_s[row * KP2 + kq] = v;
        }
        #pragma unroll
        for (int r = 0; r < 4; ++r) {               // stage B: 128x64 bf16
            int idx = tid + 256 * r;                // 0..1023
            int row = idx >> 3;
            int kq = (idx & 7) * 8;
            uint4 v = *(const uint4*)(wt_c + (size_t)row * DIM + k0 + kq);
            *(uint4*)&b_s[row * KP2 + kq] = v;
        }
        __syncthreads();
        #pragma unroll
        for (int s = 0; s < 2; ++s) {               // two K=32 steps
            int kof = s * 32 + (lane >> 4) * 8;
            bf16x8 af = *(const bf16x8*)&a_s[(wv * 16 + (lane & 15)) * KP2 + kof];
            #pragma unroll
            for (int t = 0; t < 8; ++t) {
                bf16x8 bf = *(const bf16x8*)&b_s[(t * 16 + (lane & 15)) * KP2 + kof];
                acc[t] = __builtin_amdgcn_mfma_f32_16x16x32_bf16(af, bf, acc[t], 0, 0, 0);
            }
        }
        __syncthreads();
    }

    #pragma unroll
    for (int r4 = 0; r4 < 4; ++r4) {
        int row = wv * 16 + (lane >> 4) * 4 + r4;
        if (row < mrows) {
            int nd = nl_s[row];
            float* orow = out + (size_t)nd * NCLS + (lane & 15);
            #pragma unroll
            for (int t = 0; t < 8; ++t)
                orow[t * 16] = acc[t][r4];
        }
    }
}

// --- Fallback: fused slots-based per-node kernel (f32 end-to-end) ------------

__global__ __launch_bounds__(256) void node_kernel(const float* __restrict__ h,
                                                   const int* __restrict__ cnt,
                                                   const int* __restrict__ slots,
                                                   const float* __restrict__ Ws,
                                                   const float* __restrict__ Wt,
                                                   float* __restrict__ out) {
    int node = blockIdx.x;
    int t = threadIdx.x;
    __shared__ float hm[DIM];
    __shared__ float sc[NCENT];
    __shared__ int route_s;

    int d0 = t * 2;
    float2 acc = *(const float2*)(h + (size_t)node * DIM + d0);
    int cn = cnt[node]; if (cn > WSLOT) cn = WSLOT;
    const int* sl = slots + (size_t)node * WSLOT;
    for (int j = 0; j < cn; ++j) {
        float2 v = *(const float2*)(h + (size_t)sl[j] * DIM + d0);
        acc.x += v.x; acc.y += v.y;
    }
    float inv = 1.0f / (float)(cn + 1);
    hm[d0] = acc.x * inv; hm[d0 + 1] = acc.y * inv;
    __syncthreads();
    if (t < NCENT) {
        const float* w = Ws + t * DIM;
        float s = 0.f;
        for (int d = 0; d < DIM; d += 4) {
            float4 a = *(const float4*)(&hm[d]);
            float4 b = *(const float4*)(w + d);
            s += a.x * b.x + a.y * b.y + a.z * b.z + a.w * b.w;
        }
        sc[t] = s;
    }
    __syncthreads();
    if (t == 0) {
        int best = 0; float bv = sc[0];
        #pragma unroll
        for (int c = 1; c < NCENT; ++c)
            if (sc[c] > bv) { bv = sc[c]; best = c; }
        route_s = best;
    }
    __syncthreads();
    int route = route_s;
    if (t < NCLS) {
        const float* w = Wt + ((size_t)route * NCLS + t) * DIM;
        float s = 0.f;
        for (int d = 0; d < DIM; d += 4) {
            float4 a = *(const float4*)(&hm[d]);
            float4 b = *(const float4*)(w + d);
            s += a.x * b.x + a.y * b.y + a.z * b.z + a.w * b.w;
        }
        out[(size_t)node * NCLS + t] = s;
    }
}

// --- launch ------------------------------------------------------------------

extern "C" void kernel_launch(void* const* d_in, const int* in_sizes, int n_in,
                              void* d_out, int out_size, void* d_ws, size_t ws_size,
                              hipStream_t stream) {
    const float* h   = (const float*)d_in[0];
    const int*   ei  = (const int*)d_in[1];
    const float* Ws  = (const float*)d_in[2];
    const float* Wt  = (const float*)d_in[3];
    float*       out = (float*)d_out;

    int N = in_sizes[0] / DIM;
    int E = in_sizes[1] / 2;
    int wt_elems = in_sizes[3];              // 8*128*512
    const int* esrc = ei;
    const int* edst = ei + E;

    int* wsp    = (int*)d_ws;
    int* cnt    = wsp;                       // N
    int* route  = cnt + N;                   // N
    int* goff   = route + N;                 // 9
    int* tloff  = goff + NCENT + 1;          // 9
    int* bhist  = tloff + NCENT + 1;         // NB*8
    int* nlist  = bhist + NB * NCENT;        // N
    int* slots  = nlist + N;                 // N*WSLOT
    size_t iw   = (size_t)(3 * N) + 2 * (NCENT + 1) + NB * NCENT
                + (size_t)N * WSLOT;
    size_t q_off  = ((iw * 4 + 255) & ~(size_t)255);
    float* q    = (float*)((char*)d_ws + q_off);               // N*8 f32
    size_t hb_off = ((q_off + (size_t)N * NCENT * 4 + 255) & ~(size_t)255);
    ushort_t* hb = (ushort_t*)((char*)d_ws + hb_off);          // N*512 bf16
    size_t hmb_off = ((hb_off + (size_t)N * DIM * 2 + 255) & ~(size_t)255);
    ushort_t* hmb = (ushort_t*)((char*)d_ws + hmb_off);        // N*512 bf16
    size_t wtb_off = ((hmb_off + (size_t)N * DIM * 2 + 255) & ~(size_t)255);
    ushort_t* wtb = (ushort_t*)((char*)d_ws + wtb_off);        // 8*128*512 bf16
    size_t need = wtb_off + (size_t)wt_elems * 2;

    hipMemsetAsync(cnt, 0, (size_t)N * sizeof(int), stream);

    if (ws_size >= need) {
        int nprep = (N + 3) / 4;
        int total8 = wt_elems / 8;
        int nwt = (total8 + 255) / 256;
        prep_kernel<<<nprep + nwt, 256, 0, stream>>>(h, Ws, Wt, hb, q, wtb,
                                                     N, nprep, total8);
        scatter_pad_kernel<<<(E + 255) / 256, 256, 0, stream>>>(esrc, edst, cnt, slots, E);
        gather_route_kernel<<<(N + 3) / 4, 256, 0, stream>>>(hb, cnt, slots, q,
                                                             hmb, route, N);
        route_hist_kernel<<<NB, 256, 0, stream>>>(route, bhist, N);
        scan_scatter_kernel<<<NB, 256, 0, stream>>>(bhist, route, nlist,
                                                    goff, tloff, N);
        int maxtiles = N / TM + NCENT + 1;
        gemm_mfma_kernel<<<maxtiles, 256, 0, stream>>>(hmb, nlist, goff, tloff, wtb, out);
    } else {
        scatter_pad_kernel<<<(E + 255) / 256, 256, 0, stream>>>(esrc, edst, cnt, slots, E);
        node_kernel<<<N, 256, 0, stream>>>(h, cnt, slots, Ws, Wt, out);
    }
}